// Round 1
// baseline (3421.475 us; speedup 1.0000x reference)
//
#include <hip/hip_runtime.h>
#include <math.h>

#define NB 512
#define DD 32
#define HH 128
#define NTP 64
#define NINNER 8

struct F2 { float x, y; };
__device__ __forceinline__ F2 mkf2(float a, float b) { F2 r; r.x = a; r.y = b; return r; }

__global__ __launch_bounds__(64, 1)
void ude_kernel(const float* __restrict__ gy0, const float* __restrict__ gts,
                const float* __restrict__ gW1, const float* __restrict__ gb1,
                const float* __restrict__ gW2, const float* __restrict__ gb2,
                float* __restrict__ gout)
{
    constexpr float A21 = 0.161f;
    constexpr float A31 = -0.008480655492356989f, A32 = 0.335480655492357f;
    constexpr float A41 = 2.8971530571054935f, A42 = -6.359448489975075f, A43 = 4.3622954328695815f;
    constexpr float A51 = 5.325864828439257f, A52 = -11.748883564062828f, A53 = 7.4955393428898365f, A54 = -0.09249506636175525f;
    constexpr float A61 = 5.86145544294642f, A62 = -12.92096931784711f, A63 = 8.159367898576159f, A64 = -0.071584973281401f, A65 = -0.028269050394068383f;
    constexpr float B1c = 0.09646076681806523f, B2c = 0.01f, B3c = 0.4798896504144996f,
                    B4c = 1.379008574103742f, B5c = -3.290069515436081f, B6c = 2.324710524099774f;
    constexpr float E1 = -0.001780011052225777f, E2 = -0.0008164344596567469f, E3 = 0.007880878010261995f,
                    E4 = -0.1447110071732629f, E5 = 0.5823571654525552f, E6 = -0.45808210592918697f,
                    E7 = 0.015151515151515152f;

    __shared__ alignas(16) F2 yb[DD];    // y broadcast buffer (float2 over the 2 batch elems)
    __shared__ alignas(16) F2 thb[HH];   // tanh(hidden) buffer

    const int l  = threadIdx.x;
    const int d  = l & 31;    // output dim owned in phase 2
    const int hf = l >> 5;    // which half of the hidden units this lane sums in phase 2
    const int p  = blockIdx.x;
    const int e0 = 2 * p, e1 = 2 * p + 1;   // the two batch elements

    // ---- weights resident in registers ----
    float w1a[DD], w1b[DD], w2c[64];
#pragma unroll
    for (int i = 0; i < DD; ++i) {
        w1a[i] = gW1[i * HH + l];          // W1 column l
        w1b[i] = gW1[i * HH + l + 64];     // W1 column l+64
    }
#pragma unroll
    for (int j = 0; j < 64; ++j)
        w2c[j] = gW2[(hf * 64 + j) * DD + d];  // W2 half-column for output dim d

    const float bh0 = gb1[l], bh1 = gb1[l + 64];
    const float b2d = gb2[d];

    // ---- vector field: ys is this lane's component d of y (replicated across halves) ----
    auto ftanh = [](float v) -> float {
        float e = __expf(2.0f * v);
        return 1.0f - __fdividef(2.0f, e + 1.0f);
    };

    auto vf = [&](F2 ys) -> F2 {
        if (hf == 0) yb[d] = ys;   // publish y (lanes 0-31 cover all 32 dims)
        F2 h0 = mkf2(bh0, bh0), h1 = mkf2(bh1, bh1);
        const float4* y4 = reinterpret_cast<const float4*>(yb);
#pragma unroll
        for (int i = 0; i < 16; ++i) {
            float4 v = y4[i];   // y[2i], y[2i+1] for both elems (broadcast read)
            float wa0 = w1a[2 * i], wa1 = w1a[2 * i + 1];
            float wb0 = w1b[2 * i], wb1 = w1b[2 * i + 1];
            h0.x = fmaf(v.x, wa0, h0.x); h0.y = fmaf(v.y, wa0, h0.y);
            h0.x = fmaf(v.z, wa1, h0.x); h0.y = fmaf(v.w, wa1, h0.y);
            h1.x = fmaf(v.x, wb0, h1.x); h1.y = fmaf(v.y, wb0, h1.y);
            h1.x = fmaf(v.z, wb1, h1.x); h1.y = fmaf(v.w, wb1, h1.y);
        }
        F2 t0 = mkf2(ftanh(h0.x), ftanh(h0.y));
        F2 t1 = mkf2(ftanh(h1.x), ftanh(h1.y));
        thb[l]      = t0;   // hidden unit l
        thb[l + 64] = t1;   // hidden unit l+64
        F2 acc = mkf2(0.0f, 0.0f);
        const float4* t4 = reinterpret_cast<const float4*>(thb + hf * 64);
#pragma unroll
        for (int i = 0; i < 32; ++i) {
            float4 v = t4[i];   // th[2i], th[2i+1] of this half (broadcast read)
            float wc0 = w2c[2 * i], wc1 = w2c[2 * i + 1];
            acc.x = fmaf(v.x, wc0, acc.x); acc.y = fmaf(v.y, wc0, acc.y);
            acc.x = fmaf(v.z, wc1, acc.x); acc.y = fmaf(v.w, wc1, acc.y);
        }
        // combine the two hidden halves (lanes l and l^32 hold partials of the same dim d)
        acc.x += __shfl_xor(acc.x, 32, 64);
        acc.y += __shfl_xor(acc.y, 32, 64);
        F2 r;
        r.x = fmaf(-0.5f, ys.x, acc.x + b2d);
        r.y = fmaf(-0.5f, ys.y, acc.y + b2d);
        return r;
    };

    // ---- initial state ----
    F2 y = mkf2(gy0[e0 * DD + d], gy0[e1 * DD + d]);
    const float ts0 = gts[0];
    F2 t  = mkf2(ts0, ts0);
    F2 dt = mkf2(0.05f, 0.05f);
    F2 k1 = vf(y);

    // output at ti = 0 (y0)
    {
        const int bsel = hf ? e1 : e0;
        gout[bsel * NTP * DD + d] = hf ? y.y : y.x;
    }

    for (int it = 1; it < NTP; ++it) {
        const float tb = gts[it];
#pragma unroll 1
        for (int s = 0; s < NINNER; ++s) {
            F2 dtc;
            dtc.x = fmaxf(fminf(dt.x, tb - t.x), 1e-12f);
            dtc.y = fmaxf(fminf(dt.y, tb - t.y), 1e-12f);

            F2 st, k2, k3, k4, k5, k6, k7, ynew, err;
            float sx, sy;

            // k2
            st.x = fmaf(dtc.x, A21 * k1.x, y.x);
            st.y = fmaf(dtc.y, A21 * k1.y, y.y);
            k2 = vf(st);
            // k3
            sx = A31 * k1.x; sx = fmaf(A32, k2.x, sx);
            sy = A31 * k1.y; sy = fmaf(A32, k2.y, sy);
            st.x = fmaf(dtc.x, sx, y.x); st.y = fmaf(dtc.y, sy, y.y);
            k3 = vf(st);
            // k4
            sx = A41 * k1.x; sx = fmaf(A42, k2.x, sx); sx = fmaf(A43, k3.x, sx);
            sy = A41 * k1.y; sy = fmaf(A42, k2.y, sy); sy = fmaf(A43, k3.y, sy);
            st.x = fmaf(dtc.x, sx, y.x); st.y = fmaf(dtc.y, sy, y.y);
            k4 = vf(st);
            // k5
            sx = A51 * k1.x; sx = fmaf(A52, k2.x, sx); sx = fmaf(A53, k3.x, sx); sx = fmaf(A54, k4.x, sx);
            sy = A51 * k1.y; sy = fmaf(A52, k2.y, sy); sy = fmaf(A53, k3.y, sy); sy = fmaf(A54, k4.y, sy);
            st.x = fmaf(dtc.x, sx, y.x); st.y = fmaf(dtc.y, sy, y.y);
            k5 = vf(st);
            // k6
            sx = A61 * k1.x; sx = fmaf(A62, k2.x, sx); sx = fmaf(A63, k3.x, sx); sx = fmaf(A64, k4.x, sx); sx = fmaf(A65, k5.x, sx);
            sy = A61 * k1.y; sy = fmaf(A62, k2.y, sy); sy = fmaf(A63, k3.y, sy); sy = fmaf(A64, k4.y, sy); sy = fmaf(A65, k5.y, sy);
            st.x = fmaf(dtc.x, sx, y.x); st.y = fmaf(dtc.y, sy, y.y);
            k6 = vf(st);
            // y_new
            sx = B1c * k1.x; sx = fmaf(B2c, k2.x, sx); sx = fmaf(B3c, k3.x, sx); sx = fmaf(B4c, k4.x, sx); sx = fmaf(B5c, k5.x, sx); sx = fmaf(B6c, k6.x, sx);
            sy = B1c * k1.y; sy = fmaf(B2c, k2.y, sy); sy = fmaf(B3c, k3.y, sy); sy = fmaf(B4c, k4.y, sy); sy = fmaf(B5c, k5.y, sy); sy = fmaf(B6c, k6.y, sy);
            ynew.x = fmaf(dtc.x, sx, y.x); ynew.y = fmaf(dtc.y, sy, y.y);
            k7 = vf(ynew);
            // err
            sx = E1 * k1.x; sx = fmaf(E2, k2.x, sx); sx = fmaf(E3, k3.x, sx); sx = fmaf(E4, k4.x, sx); sx = fmaf(E5, k5.x, sx); sx = fmaf(E6, k6.x, sx); sx = fmaf(E7, k7.x, sx);
            sy = E1 * k1.y; sy = fmaf(E2, k2.y, sy); sy = fmaf(E3, k3.y, sy); sy = fmaf(E4, k4.y, sy); sy = fmaf(E5, k5.y, sy); sy = fmaf(E6, k6.y, sy); sy = fmaf(E7, k7.y, sy);
            err.x = dtc.x * sx; err.y = dtc.y * sy;

            // error norm over the 32 dims (each half-wave holds a full replica)
            float tolx = fmaf(0.001f, fmaxf(fabsf(y.x), fabsf(ynew.x)), 1e-06f);
            float toly = fmaf(0.001f, fmaxf(fabsf(y.y), fabsf(ynew.y)), 1e-06f);
            float qx = err.x / tolx; qx *= qx;
            float qy = err.y / toly; qy *= qy;
#pragma unroll
            for (int m = 1; m <= 16; m <<= 1) {
                qx += __shfl_xor(qx, m, 64);
                qy += __shfl_xor(qy, m, 64);
            }
            const float enx = sqrtf(qx * (1.0f / 32.0f));
            const float eny = sqrtf(qy * (1.0f / 32.0f));

            const bool donex = (t.x >= tb - 1e-9f);
            const bool doney = (t.y >= tb - 1e-9f);
            const bool accx  = (enx <= 1.0f) && !donex;
            const bool accy  = (eny <= 1.0f) && !doney;

            float fx = 0.9f * __powf(fmaxf(enx, 1e-10f), -0.2f);
            float fy = 0.9f * __powf(fmaxf(eny, 1e-10f), -0.2f);
            fx = fminf(fmaxf(fx, 0.1f), 5.0f);
            fy = fminf(fmaxf(fy, 0.1f), 5.0f);

            dt.x = donex ? dt.x : dtc.x * fx;
            dt.y = doney ? dt.y : dtc.y * fy;
            t.x  = accx ? (t.x + dtc.x) : t.x;
            t.y  = accy ? (t.y + dtc.y) : t.y;
            y.x  = accx ? ynew.x : y.x;
            y.y  = accy ? ynew.y : y.y;
            k1.x = accx ? k7.x : k1.x;
            k1.y = accy ? k7.y : k1.y;
        }
        const int bsel = hf ? e1 : e0;
        gout[bsel * NTP * DD + it * DD + d] = hf ? y.y : y.x;
    }
}

extern "C" void kernel_launch(void* const* d_in, const int* in_sizes, int n_in,
                              void* d_out, int out_size, void* d_ws, size_t ws_size,
                              hipStream_t stream) {
    (void)in_sizes; (void)n_in; (void)out_size; (void)d_ws; (void)ws_size;
    const float* y0 = (const float*)d_in[0];
    const float* ts = (const float*)d_in[1];
    const float* W1 = (const float*)d_in[2];
    const float* b1 = (const float*)d_in[3];
    const float* W2 = (const float*)d_in[4];
    const float* b2 = (const float*)d_in[5];
    ude_kernel<<<dim3(NB / 2), dim3(64), 0, stream>>>(y0, ts, W1, b1, W2, b2, (float*)d_out);
}

// Round 3
// 247.593 us; speedup vs baseline: 13.8190x; 13.8190x over previous
//
#include <hip/hip_runtime.h>

typedef float f32x2 __attribute__((ext_vector_type(2)));
typedef float f32x4 __attribute__((ext_vector_type(4)));

#define NB 512
#define DD 32
#define HH 128
#define NTP 64
#define NINNER 8

// packed dual-FP32 FMA: acc.lo += a.lo*b.lo ; acc.hi += a.hi*b.hi
__device__ __forceinline__ void pk_fma2(f32x2& acc, f32x2 a, f32x2 b) {
    asm("v_pk_fma_f32 %0, %1, %2, %0" : "+v"(acc) : "v"(a), "v"(b));
}
// hardware transcendentals (avoid glibc math.h name collisions entirely)
__device__ __forceinline__ float fexp2(float x) { float r; asm("v_exp_f32 %0, %1" : "=v"(r) : "v"(x)); return r; }
__device__ __forceinline__ float flog2(float x) { float r; asm("v_log_f32 %0, %1" : "=v"(r) : "v"(x)); return r; }
__device__ __forceinline__ float frcpa(float x) { float r; asm("v_rcp_f32 %0, %1" : "=v"(r) : "v"(x)); return r; }

__global__ __launch_bounds__(128, 1)
void ude_kernel(const float* __restrict__ gy0, const float* __restrict__ gts,
                const float* __restrict__ gW1, const float* __restrict__ gb1,
                const float* __restrict__ gW2, const float* __restrict__ gb2,
                float* __restrict__ gout)
{
    constexpr float A21 = 0.161f;
    constexpr float A31 = -0.008480655492356989f, A32 = 0.335480655492357f;
    constexpr float A41 = 2.8971530571054935f, A42 = -6.359448489975075f, A43 = 4.3622954328695815f;
    constexpr float A51 = 5.325864828439257f, A52 = -11.748883564062828f, A53 = 7.4955393428898365f, A54 = -0.09249506636175525f;
    constexpr float A61 = 5.86145544294642f, A62 = -12.92096931784711f, A63 = 8.159367898576159f, A64 = -0.071584973281401f, A65 = -0.028269050394068383f;
    constexpr float B1c = 0.09646076681806523f, B2c = 0.01f, B3c = 0.4798896504144996f,
                    B4c = 1.379008574103742f, B5c = -3.290069515436081f, B6c = 2.324710524099774f;
    constexpr float E1 = -0.001780011052225777f, E2 = -0.0008164344596567469f, E3 = 0.007880878010261995f,
                    E4 = -0.1447110071732629f, E5 = 0.5823571654525552f, E6 = -0.45808210592918697f,
                    E7 = 0.015151515151515152f;

    // per-wave private LDS (2 waves per block, no barriers anywhere)
    __shared__ alignas(16) float ybuf[2][64];
    __shared__ alignas(16) float thb[2][HH];

    const int tid = threadIdx.x;
    const int wid = tid >> 6;        // wave in block
    const int l   = tid & 63;        // lane
    const int d   = l & 31;          // dim owned (replicated across halves)
    const int hf  = l >> 5;          // hidden-half owned in phase 2
    const int e   = blockIdx.x * 2 + wid;   // batch element (1 per wave)

    float* yb = ybuf[wid];
    float* th = thb[wid];

    // ---- weights resident in registers, pre-paired over the K dimension ----
    f32x2 w1a2[16], w1b2[16], w2p[32];
#pragma unroll
    for (int i = 0; i < 16; ++i) {
        w1a2[i][0] = gW1[(2 * i) * HH + l];          // W1[2i  ][l]
        w1a2[i][1] = gW1[(2 * i + 1) * HH + l];      // W1[2i+1][l]
        w1b2[i][0] = gW1[(2 * i) * HH + l + 64];     // W1[2i  ][l+64]
        w1b2[i][1] = gW1[(2 * i + 1) * HH + l + 64];
    }
#pragma unroll
    for (int j = 0; j < 32; ++j) {
        const int h0 = hf * 64 + 2 * j;
        w2p[j][0] = gW2[h0 * DD + d];
        w2p[j][1] = gW2[(h0 + 1) * DD + d];
    }
    const float bh0 = gb1[l], bh1 = gb1[l + 64], b2d = gb2[d];

    auto ftanh = [](float v) -> float {
        // tanh(v) = 1 - 2/(exp(2v)+1); exp via v_exp_f32 (2^x)
        float ex = fexp2(v * 2.885390081777927f);   // 2*log2(e)
        return 1.0f - frcpa(ex + 1.0f) * 2.0f;
    };

    // vector field: ys = this lane's component d of y (replicated across halves)
    auto vf = [&](float ys) -> float {
        yb[l] = ys;                               // lanes 0..31 publish dims; 32..63 write unused replicas
        f32x2 ha = {0.f, 0.f}, hb = {0.f, 0.f}, hc = {0.f, 0.f}, hd = {0.f, 0.f};
        const f32x4* y4 = (const f32x4*)yb;
#pragma unroll
        for (int i = 0; i < 8; ++i) {
            f32x4 v = y4[i];                      // y[4i..4i+3], wave-broadcast read
            f32x2 vlo = {v[0], v[1]}, vhi = {v[2], v[3]};
            pk_fma2(ha, vlo, w1a2[2 * i]);        // hidden unit l
            pk_fma2(hb, vhi, w1a2[2 * i + 1]);
            pk_fma2(hc, vlo, w1b2[2 * i]);        // hidden unit l+64
            pk_fma2(hd, vhi, w1b2[2 * i + 1]);
        }
        const float h0 = bh0 + (ha[0] + ha[1]) + (hb[0] + hb[1]);
        const float h1 = bh1 + (hc[0] + hc[1]) + (hd[0] + hd[1]);
        const float t0 = ftanh(h0);
        const float t1 = ftanh(h1);
        th[l] = t0;
        th[l + 64] = t1;

        f32x2 a0 = {0.f, 0.f}, a1 = {0.f, 0.f}, a2 = {0.f, 0.f}, a3 = {0.f, 0.f};
        const f32x4* t4 = (const f32x4*)(th + (hf << 6));
#pragma unroll
        for (int i = 0; i < 4; ++i) {
            f32x4 va = t4[4 * i + 0], vb = t4[4 * i + 1], vc = t4[4 * i + 2], vd = t4[4 * i + 3];
            pk_fma2(a0, f32x2{va[0], va[1]}, w2p[8 * i + 0]);
            pk_fma2(a0, f32x2{va[2], va[3]}, w2p[8 * i + 1]);
            pk_fma2(a1, f32x2{vb[0], vb[1]}, w2p[8 * i + 2]);
            pk_fma2(a1, f32x2{vb[2], vb[3]}, w2p[8 * i + 3]);
            pk_fma2(a2, f32x2{vc[0], vc[1]}, w2p[8 * i + 4]);
            pk_fma2(a2, f32x2{vc[2], vc[3]}, w2p[8 * i + 5]);
            pk_fma2(a3, f32x2{vd[0], vd[1]}, w2p[8 * i + 6]);
            pk_fma2(a3, f32x2{vd[2], vd[3]}, w2p[8 * i + 7]);
        }
        f32x2 asum = (a0 + a1) + (a2 + a3);
        float s = asum[0] + asum[1];
        s += __shfl_xor(s, 32, 64);               // combine the two hidden halves
        return fmaf(-0.5f, ys, s + b2d);
    };

    // ---- initial state ----
    float y  = gy0[e * DD + d];
    float t  = gts[0];
    float dt = 0.05f;
    float k1 = vf(y);

    if (l < 32) gout[e * NTP * DD + l] = y;       // ti = 0 output

#pragma unroll 1
    for (int it = 1; it < NTP; ++it) {
        const float tb = gts[it];
#pragma unroll 1
        for (int s = 0; s < NINNER; ++s) {
            if (t >= tb - 1e-9f) break;           // wave-uniform: remaining iters are provable no-ops

            const float dtc = fmaxf(fminf(dt, tb - t), 1e-12f);

            float st, sx;
            // k2
            st = fmaf(dtc, A21 * k1, y);
            const float k2 = vf(st);
            // k3
            sx = fmaf(A32, k2, A31 * k1);
            st = fmaf(dtc, sx, y);
            const float k3 = vf(st);
            // k4
            sx = A41 * k1; sx = fmaf(A42, k2, sx); sx = fmaf(A43, k3, sx);
            st = fmaf(dtc, sx, y);
            const float k4 = vf(st);
            // k5
            sx = A51 * k1; sx = fmaf(A52, k2, sx); sx = fmaf(A53, k3, sx); sx = fmaf(A54, k4, sx);
            st = fmaf(dtc, sx, y);
            const float k5 = vf(st);
            // k6
            sx = A61 * k1; sx = fmaf(A62, k2, sx); sx = fmaf(A63, k3, sx); sx = fmaf(A64, k4, sx); sx = fmaf(A65, k5, sx);
            st = fmaf(dtc, sx, y);
            const float k6 = vf(st);
            // y_new
            sx = B1c * k1; sx = fmaf(B2c, k2, sx); sx = fmaf(B3c, k3, sx);
            sx = fmaf(B4c, k4, sx); sx = fmaf(B5c, k5, sx); sx = fmaf(B6c, k6, sx);
            const float ynew = fmaf(dtc, sx, y);
            const float k7 = vf(ynew);
            // err
            sx = E1 * k1; sx = fmaf(E2, k2, sx); sx = fmaf(E3, k3, sx); sx = fmaf(E4, k4, sx);
            sx = fmaf(E5, k5, sx); sx = fmaf(E6, k6, sx); sx = fmaf(E7, k7, sx);
            const float err = dtc * sx;

            // error norm over 32 dims (each 32-lane half holds a full replica)
            const float tol = fmaf(0.001f, fmaxf(fabsf(y), fabsf(ynew)), 1e-06f);
            float q = __fdividef(err, tol);
            q *= q;
#pragma unroll
            for (int m = 1; m <= 16; m <<= 1)
                q += __shfl_xor(q, m, 64);
            const float en2 = q * (1.0f / 32.0f);        // en^2

            const bool acc = (en2 <= 1.0f);              // en<=1  <=>  en2<=1
            // factor = clip(0.9 * en^-0.2, 0.1, 5) ;  en^-0.2 = (en2)^-0.1
            float fac = 0.9f * fexp2(-0.1f * flog2(fmaxf(en2, 1e-20f)));
            fac = fminf(fmaxf(fac, 0.1f), 5.0f);

            dt = dtc * fac;                              // done==false inside the loop
            t  = acc ? (t + dtc) : t;
            y  = acc ? ynew : y;
            k1 = acc ? k7 : k1;
        }
        if (l < 32) gout[e * NTP * DD + it * DD + l] = y;
    }
}

extern "C" void kernel_launch(void* const* d_in, const int* in_sizes, int n_in,
                              void* d_out, int out_size, void* d_ws, size_t ws_size,
                              hipStream_t stream) {
    (void)in_sizes; (void)n_in; (void)out_size; (void)d_ws; (void)ws_size;
    const float* y0 = (const float*)d_in[0];
    const float* ts = (const float*)d_in[1];
    const float* W1 = (const float*)d_in[2];
    const float* b1 = (const float*)d_in[3];
    const float* W2 = (const float*)d_in[4];
    const float* b2 = (const float*)d_in[5];
    ude_kernel<<<dim3(NB / 2), dim3(128), 0, stream>>>(y0, ts, W1, b1, W2, b2, (float*)d_out);
}